// Round 2
// 389.762 us; speedup vs baseline: 1.0531x; 1.0531x over previous
//
#include <hip/hip_runtime.h>
#include <hip/hip_bf16.h>
#include <math.h>

#define DIM 2048
#define NH 16
#define HD 128
#define WIN 512

typedef __hip_bfloat16 bf16;
using frag8 = __attribute__((ext_vector_type(8))) short;  // 8 bf16 (4 VGPRs)
using facc4 = __attribute__((ext_vector_type(4))) float;  // 4 fp32 acc

// ---------- conversion helpers ----------
__device__ inline float toF(const bf16 v) { return __bfloat162float(v); }
template <typename T> __device__ inline T fromF(float v);
template <> __device__ inline float fromF<float>(float v) { return v; }
template <> __device__ inline bf16 fromF<bf16>(float v) { return __float2bfloat16(v); }

// fp32 -> bf16 bits, round-to-nearest-even
__device__ inline unsigned bfb(float x) {
    unsigned u = __float_as_uint(x);
    u += 0x7fffu + ((u >> 16) & 1u);
    return u >> 16;
}

// pack 8 fp32 -> 8 bf16 (one uint4)
__device__ inline uint4 pack8(const float* p) {
    const float4 v0 = *(const float4*)p;
    const float4 v1 = *(const float4*)(p + 4);
    uint4 r;
    r.x = bfb(v0.x) | (bfb(v0.y) << 16);
    r.y = bfb(v0.z) | (bfb(v0.w) << 16);
    r.z = bfb(v1.x) | (bfb(v1.y) << 16);
    r.w = bfb(v1.z) | (bfb(v1.w) << 16);
    return r;
}

// ---------- fp32 -> bf16 bulk convert ----------
__global__ __launch_bounds__(256) void cvt_f32_bf16(const float* __restrict__ src,
                                                    bf16* __restrict__ dst, int n8) {
    const int i = blockIdx.x * 256 + threadIdx.x;
    if (i < n8) ((uint4*)dst)[i] = pack8(src + (size_t)i * 8);
}

// ---------- async global->LDS, 16B per lane, wave-uniform LDS base ----------
__device__ inline void gload_lds16(const bf16* g, short* l) {
    __builtin_amdgcn_global_load_lds(
        (const __attribute__((address_space(1))) unsigned int*)g,
        (__attribute__((address_space(3))) unsigned int*)l, 16, 0, 0);
}

// ===================================================================================
// 256x256 8-phase GEMM (m201-style): C[m,n] = sum_k A[m,k]*B[n,k], bf16 in.
// 512 thr = 8 waves (2Mx4N), per-wave 128x64 out, BK=64, 2 K-tiles / iteration.
// LDS 128 KiB double-buffered; staging via global_load_lds w/ pre-swizzled source
// (slot ^= row&7) so ds_read_b128 is conflict-free; counted vmcnt(6) at ph4/ph8
// only (3 staging units in flight, never drained to 0 in the main loop).
// Staging unit p = exactly the rows quadrant-phase p frees:
//   U0 = A rows {0-63,128-191} (mi=0)     read in PH1 -> restaged PH2
//   U3 = B rows {32-63,96-127,...} (ni=1) read in PH2 -> restaged PH4 (prev tile: PH8)
//   U1 = A rows {64-127,192-255} (mi=1)   read in PH3 -> restaged PH5 (prev: PH1)
//   U2 = B rows {0-31,64-95,...} (ni=0)   read in PH1 -> restaged PH3
// vmcnt ledger (units, 2 VMEM ops each): steady state holds 7 units in flight at
// each gate; vmcnt(6)=12ops? no — vmcnt counts OPS: 14 ops in flight, vmcnt(6)
// retires the 8 oldest = exactly the 4 units of the tile consumed next.
// ===================================================================================

#define WAIT_LGKM0()                                             \
    do {                                                         \
        asm volatile("s_waitcnt lgkmcnt(0)" ::: "memory");       \
        __builtin_amdgcn_sched_barrier(0);                       \
    } while (0)

#define READ_A(BUF, MI)                                                          \
    do {                                                                         \
        _Pragma("unroll") for (int ii = 0; ii < 4; ++ii)                         \
        _Pragma("unroll") for (int kk = 0; kk < 2; ++kk) {                       \
            const int row_ = wm * 128 + (MI) * 64 + ii * 16 + mr;                \
            const int slot_ = ((kk << 2) + q) ^ (row_ & 7);                      \
            a[ii][kk] = *(const frag8*)&lds[BUF][0][row_][slot_ << 3];           \
        }                                                                        \
    } while (0)

#define READ_B(BUF, NI)                                                          \
    do {                                                                         \
        _Pragma("unroll") for (int jj = 0; jj < 2; ++jj)                         \
        _Pragma("unroll") for (int kk = 0; kk < 2; ++kk) {                       \
            const int row_ = wn * 64 + (NI) * 32 + jj * 16 + mr;                 \
            const int slot_ = ((kk << 2) + q) ^ (row_ & 7);                      \
            b[NI][jj][kk] = *(const frag8*)&lds[BUF][1][row_][slot_ << 3];       \
        }                                                                        \
    } while (0)

#define MFMA_QUAD(MI, NI)                                                        \
    do {                                                                         \
        __builtin_amdgcn_s_setprio(1);                                           \
        _Pragma("unroll") for (int ii = 0; ii < 4; ++ii)                         \
        _Pragma("unroll") for (int jj = 0; jj < 2; ++jj)                         \
        _Pragma("unroll") for (int kk = 0; kk < 2; ++kk)                         \
            acc[(MI) * 4 + ii][(NI) * 2 + jj] =                                  \
                __builtin_amdgcn_mfma_f32_16x16x32_bf16(                         \
                    a[ii][kk], b[NI][jj][kk], acc[(MI) * 4 + ii][(NI) * 2 + jj], \
                    0, 0, 0);                                                    \
        __builtin_amdgcn_s_setprio(0);                                           \
    } while (0)

template <typename TC, bool SPLIT>
__global__ __launch_bounds__(512, 2) void gemm256_8ph(const bf16* __restrict__ A,
                                                      const bf16* __restrict__ B,
                                                      TC* __restrict__ C,
                                                      bf16* __restrict__ Qp,
                                                      bf16* __restrict__ Kp,
                                                      bf16* __restrict__ Vp,
                                                      int M, int N, int K) {
    __shared__ __align__(16) short lds[2][2][256][64];  // [dbuf][A/B][row][k] 128 KiB
    const int tid = threadIdx.x;
    const int lane = tid & 63;
    const int w = tid >> 6;

    // XCD-aware block swizzle (guarded: only when nwg % 8 == 0 -> bijective)
    const int gx = gridDim.x;
    const int nwg = gx * (int)gridDim.y;
    const int lin0 = (int)blockIdx.y * gx + (int)blockIdx.x;
    const int lin = ((nwg & 7) == 0) ? (lin0 & 7) * (nwg >> 3) + (lin0 >> 3) : lin0;
    const int n0 = (lin % gx) * 256;
    const int m0 = (lin / gx) * 256;

    const int wm = w >> 2, wn = w & 3;
    const int q = lane >> 4, mr = lane & 15;
    const int sl = lane & 7, rlo = lane >> 3;
    const int rbA = wm * 128 + wn * 16;            // U0 wave base; U1 = +64
    const int rbB = (w >> 1) * 64 + (w & 1) * 16;  // U2 wave base; U3 = +32

    const int nt = K >> 6;  // K-tiles; requires K % 128 == 0
    const int nIter = nt >> 1;

    facc4 acc[8][4];
#pragma unroll
    for (int i = 0; i < 8; ++i)
#pragma unroll
        for (int j = 0; j < 4; ++j)
#pragma unroll
            for (int r = 0; r < 4; ++r) acc[i][j][r] = 0.f;

    frag8 a[4][2], b[2][2][2];

    // one staging unit = 16 KiB = 2 x global_load_lds(16B) per thread.
    // LDS dest is linear (gload constraint); the XOR swizzle is applied by
    // permuting the per-lane GLOBAL source chunk (slot sl fetches chunk sl^rlo),
    // so LDS[r][sl] = global[r][sl ^ (r&7)] and the read XORs it back.
    auto stage = [&](const bf16* __restrict__ G, int grb, int mat, int buf, int ub, int t) {
        const int kt = t < nt ? t : nt - 1;  // clamp: tail stages read valid mem, never consumed
        const int k0 = kt << 6;
#pragma unroll
        for (int u = 0; u < 2; ++u) {
            const int row0 = ub + u * 8;  // wave-uniform, multiple of 8
            const int row = row0 + rlo;
            gload_lds16(G + (size_t)(grb + row) * K + k0 + ((sl ^ rlo) << 3),
                        (short*)&lds[buf][mat][row0][0]);
        }
    };

    // ---- prologue: tile0 -> buf0 (all 4 units); tile1 -> buf1 (U0,U2,U3) ----
    stage(A, m0, 0, 0, rbA, 0);
    stage(A, m0, 0, 0, rbA + 64, 0);
    stage(B, n0, 1, 0, rbB, 0);
    stage(B, n0, 1, 0, rbB + 32, 0);
    stage(A, m0, 0, 1, rbA, 1);
    stage(B, n0, 1, 1, rbB, 1);
    stage(B, n0, 1, 1, rbB + 32, 1);
    asm volatile("s_waitcnt vmcnt(6)" ::: "memory");  // tile0 fully landed
    __builtin_amdgcn_s_barrier();

    for (int it = 0; it < nIter; ++it) {
        const int t2 = 2 * it + 2;
        // ================ K-tile 2it (buf0) ================
        // PH1: quad (0,0)
        READ_A(0, 0);
        READ_B(0, 0);
        stage(A, m0, 0, 1, rbA + 64, 2 * it + 1);  // U1(2it+1) -> buf1
        __builtin_amdgcn_s_barrier();
        WAIT_LGKM0();
        MFMA_QUAD(0, 0);
        __builtin_amdgcn_s_barrier();
        // PH2: quad (0,1)
        READ_B(0, 1);
        stage(A, m0, 0, 0, rbA, t2);               // U0(t2) -> buf0
        __builtin_amdgcn_s_barrier();
        WAIT_LGKM0();
        MFMA_QUAD(0, 1);
        __builtin_amdgcn_s_barrier();
        // PH3: quad (1,0)
        READ_A(0, 1);
        stage(B, n0, 1, 0, rbB, t2);               // U2(t2) -> buf0
        __builtin_amdgcn_s_barrier();
        WAIT_LGKM0();
        MFMA_QUAD(1, 0);
        __builtin_amdgcn_s_barrier();
        // PH4: quad (1,1) — buffer-switch gate
        stage(B, n0, 1, 0, rbB + 32, t2);          // U3(t2) -> buf0
        __builtin_amdgcn_s_barrier();
        __builtin_amdgcn_sched_barrier(0);
        MFMA_QUAD(1, 1);
        asm volatile("s_waitcnt vmcnt(6)" ::: "memory");  // tile 2it+1 landed
        __builtin_amdgcn_s_barrier();
        // ================ K-tile 2it+1 (buf1) ================
        // PH5: quad (0,0)
        READ_A(1, 0);
        READ_B(1, 0);
        stage(A, m0, 0, 0, rbA + 64, t2);          // U1(t2) -> buf0
        __builtin_amdgcn_s_barrier();
        WAIT_LGKM0();
        MFMA_QUAD(0, 0);
        __builtin_amdgcn_s_barrier();
        // PH6: quad (0,1)
        READ_B(1, 1);
        stage(A, m0, 0, 1, rbA, t2 + 1);           // U0(t2+1) -> buf1
        __builtin_amdgcn_s_barrier();
        WAIT_LGKM0();
        MFMA_QUAD(0, 1);
        __builtin_amdgcn_s_barrier();
        // PH7: quad (1,0)
        READ_A(1, 1);
        stage(B, n0, 1, 1, rbB, t2 + 1);           // U2(t2+1) -> buf1
        __builtin_amdgcn_s_barrier();
        WAIT_LGKM0();
        MFMA_QUAD(1, 0);
        __builtin_amdgcn_s_barrier();
        // PH8: quad (1,1) — buffer-switch gate
        stage(B, n0, 1, 1, rbB + 32, t2 + 1);      // U3(t2+1) -> buf1
        __builtin_amdgcn_s_barrier();
        __builtin_amdgcn_sched_barrier(0);
        MFMA_QUAD(1, 1);
        asm volatile("s_waitcnt vmcnt(6)" ::: "memory");  // tile t2 landed
        __builtin_amdgcn_s_barrier();
    }

    // ---- epilogue ----
    if (SPLIT) {
        bf16* dst = (n0 < DIM) ? Qp : ((n0 < 2 * DIM) ? Kp : Vp);
        const int nb = n0 % DIM;
#pragma unroll
        for (int im = 0; im < 8; ++im)
#pragma unroll
            for (int jn = 0; jn < 4; ++jn) {
                const int col = nb + wn * 64 + jn * 16 + mr;
#pragma unroll
                for (int r = 0; r < 4; ++r) {
                    const int row = m0 + wm * 128 + im * 16 + q * 4 + r;
                    dst[(size_t)row * DIM + col] = fromF<bf16>(acc[im][jn][r]);
                }
            }
    } else {
#pragma unroll
        for (int im = 0; im < 8; ++im)
#pragma unroll
            for (int jn = 0; jn < 4; ++jn) {
                const int col = n0 + wn * 64 + jn * 16 + mr;
#pragma unroll
                for (int r = 0; r < 4; ++r) {
                    const int row = m0 + wm * 128 + im * 16 + q * 4 + r;
                    C[(size_t)row * N + col] = fromF<TC>(acc[im][jn][r]);
                }
            }
    }
}

// ---------- MFMA GEMM (m97 structure), kept for the Wo projection ----------
// (256-tile kernel would give only 128 workgroups there -> half the CUs idle.)
template <typename TC>
__global__ __launch_bounds__(256) void gemm_bt_async(const bf16* __restrict__ A,
                                                     const bf16* __restrict__ B,
                                                     TC* __restrict__ C,
                                                     int M, int N, int K) {
    __shared__ short As[128 * 32];  // row-major [row][k], no padding (global_load_lds constraint)
    __shared__ short Bs[128 * 32];
    const int tid = threadIdx.x;
    const int lane = tid & 63;
    const int w = tid >> 6;
    const int m0 = blockIdx.y * 128;
    const int n0 = blockIdx.x * 128;
    const int wm = (w >> 1) * 64;
    const int wn = (w & 1) * 64;
    const int q = lane >> 4;
    const int mr = lane & 15;

    facc4 acc[4][4];
#pragma unroll
    for (int i = 0; i < 4; ++i)
#pragma unroll
        for (int j = 0; j < 4; ++j)
#pragma unroll
            for (int r = 0; r < 4; ++r) acc[i][j][r] = 0.f;

    for (int k0 = 0; k0 < K; k0 += 32) {
        __syncthreads();
#pragma unroll
        for (int u = 0; u < 2; ++u) {
            const int c = w * 128 + u * 64 + lane;
            const int row = c >> 2, col = (c & 3) * 8;
            gload_lds16(A + (size_t)(m0 + row) * K + k0 + col, As + (w * 128 + u * 64) * 8);
            gload_lds16(B + (size_t)(n0 + row) * K + k0 + col, Bs + (w * 128 + u * 64) * 8);
        }
        __syncthreads();

        frag8 af[4], bfr[4];
#pragma unroll
        for (int i = 0; i < 4; ++i)
            af[i] = *(const frag8*)&As[(wm + 16 * i + mr) * 32 + q * 8];
#pragma unroll
        for (int j = 0; j < 4; ++j)
            bfr[j] = *(const frag8*)&Bs[(wn + 16 * j + mr) * 32 + q * 8];
#pragma unroll
        for (int i = 0; i < 4; ++i)
#pragma unroll
            for (int j = 0; j < 4; ++j)
                acc[i][j] = __builtin_amdgcn_mfma_f32_16x16x32_bf16(af[i], bfr[j], acc[i][j], 0, 0, 0);
    }

#pragma unroll
    for (int i = 0; i < 4; ++i)
#pragma unroll
        for (int j = 0; j < 4; ++j) {
            const int col = n0 + wn + 16 * j + mr;
#pragma unroll
            for (int r = 0; r < 4; ++r) {
                const int row = m0 + wm + 16 * i + q * 4 + r;
                C[(size_t)row * N + col] = fromF<TC>(acc[i][j][r]);
            }
        }
}

// ---------- vectorized RoPE: 8 elems (4 pairs) per thread ----------
__device__ inline uint rot_pair(uint wp, float c, float s) {
    const float x1 = __uint_as_float((wp & 0xFFFFu) << 16);
    const float x2 = __uint_as_float(wp & 0xFFFF0000u);
    const float r1 = x1 * c - x2 * s;
    const float r2 = x1 * s + x2 * c;
    return bfb(r1) | (bfb(r2) << 16);
}

__global__ __launch_bounds__(256) void rope_qk_vec(bf16* __restrict__ Q,
                                                   bf16* __restrict__ K, int S) {
    const int p = blockIdx.x * 256 + threadIdx.x;  // p < S*DIM/8
    const int per_row = DIM / 8;
    const int s = p / per_row;
    const int off = (p % per_row) * 8;
    const int f0 = (off & 127) >> 1;  // pair index within head
    float cs[4], sn[4];
#pragma unroll
    for (int t = 0; t < 4; ++t) {
        // inv_freq = 10000^(-(f0+t)/64) = exp(-0.14391157*(f0+t)); relative-rotation
        // property of RoPE makes the ~1e-6 rel freq error harmless.
        const float inv = __expf(-0.14391157f * (float)(f0 + t));
        sincosf((float)s * inv, &sn[t], &cs[t]);
    }
    const size_t base = (size_t)s * DIM + off;
    uint4 qv = *(uint4*)(Q + base);
    qv.x = rot_pair(qv.x, cs[0], sn[0]);
    qv.y = rot_pair(qv.y, cs[1], sn[1]);
    qv.z = rot_pair(qv.z, cs[2], sn[2]);
    qv.w = rot_pair(qv.w, cs[3], sn[3]);
    *(uint4*)(Q + base) = qv;
    uint4 kv = *(uint4*)(K + base);
    kv.x = rot_pair(kv.x, cs[0], sn[0]);
    kv.y = rot_pair(kv.y, cs[1], sn[1]);
    kv.z = rot_pair(kv.z, cs[2], sn[2]);
    kv.w = rot_pair(kv.w, cs[3], sn[3]);
    *(uint4*)(K + base) = kv;
}

// ---------- one-time V transpose: V[s][h*128+d] -> Vt[h][d][s] ----------
__global__ __launch_bounds__(256) void transp_v(const bf16* __restrict__ V,
                                                bf16* __restrict__ Vt, int S) {
    const int tid = threadIdx.x;
    const int lane = tid & 63;
    const int w = tid >> 6;
    const int k0 = blockIdx.x * 64;
    const int h = blockIdx.y;
#pragma unroll
    for (int it = 0; it < 2; ++it) {
        const int kp = lane & 31;                     // key pair 2kp, 2kp+1
        const int dc = (lane >> 5) + 2 * it + 4 * w;  // d-chunk 0..15
        const int d0 = dc * 8;
        const bf16* vp = V + (size_t)(k0 + 2 * kp) * DIM + h * HD + d0;
        const uint4 a = *(const uint4*)vp;
        const uint4 b = *(const uint4*)(vp + DIM);
        const uint aw[4] = {a.x, a.y, a.z, a.w};
        const uint bw[4] = {b.x, b.y, b.z, b.w};
#pragma unroll
        for (int e = 0; e < 8; ++e) {
            const uint lo = (aw[e >> 1] >> (16 * (e & 1))) & 0xFFFFu;
            const uint hi = (bw[e >> 1] >> (16 * (e & 1))) & 0xFFFFu;
            ((uint*)Vt)[((((size_t)h * HD + d0 + e) * S + k0) >> 1) + kp] = lo | (hi << 16);
        }
    }
}

// ---------- flash sliding-window attention (reads pre-transposed Vt) ----------
// Block = 64 queries x 1 head, 256 threads (4 waves, wave w owns query rows w*16..w*16+15).
// LDS: Qs[64][136] (reused as Ps[64][72]) | Ks[64][136] | VtL[128][72]  = 53248 B -> 3 blocks/CU.
__global__ __launch_bounds__(256, 3) void flash_swa(const bf16* __restrict__ Q,
                                                    const bf16* __restrict__ K,
                                                    const bf16* __restrict__ Vt,
                                                    bf16* __restrict__ O, int S) {
    __shared__ __align__(16) char lds[53248];
    short* Qs = (short*)lds;               // [64][136]
    short* Ps = (short*)lds;               // [64][72], reuses Qs space
    short* Ks = (short*)(lds + 17408);     // [64][136]
    short* VtL = (short*)(lds + 34816);    // [128][72]  (VtL[d][k])

    const int tid = threadIdx.x;
    const int lane = tid & 63;
    const int w = tid >> 6;
    const int q = lane >> 4;
    const int mr = lane & 15;
    const int i0 = blockIdx.x * 64;
    const int h = blockIdx.y;
    const float scale = 0.08838834764831845f;

#pragma unroll
    for (int u = 0; u < 4; ++u) {
        const int c = tid + 256 * u;
        const int row = c >> 4, col = (c & 15) * 8;
        *(uint4*)&Qs[row * 136 + col] =
            *(const uint4*)(Q + (size_t)(i0 + row) * DIM + h * HD + col);
    }
    __syncthreads();
    frag8 qf[4];
#pragma unroll
    for (int kk = 0; kk < 4; ++kk)
        qf[kk] = *(const frag8*)&Qs[(w * 16 + mr) * 136 + kk * 32 + q * 8];

    float mrow[4], lrow[4];
    facc4 oacc[8];
#pragma unroll
    for (int r = 0; r < 4; ++r) { mrow[r] = -1e30f; lrow[r] = 0.f; }
#pragma unroll
    for (int dt = 0; dt < 8; ++dt)
#pragma unroll
        for (int r = 0; r < 4; ++r) oacc[dt][r] = 0.f;

    const bf16* vtg = Vt + (size_t)h * HD * S;

    const int t0 = (i0 >= WIN) ? 0 : (WIN - i0) / 64;
    for (int t = t0; t < 9; ++t) {
        const int jb = i0 - WIN + t * 64;
        __syncthreads();

        // ---- stage K tile (64x128) ----
#pragma unroll
        for (int u = 0; u < 4; ++u) {
            const int c = tid + 256 * u;
            const int row = c >> 4, col = (c & 15) * 8;
            *(uint4*)&Ks[row * 136 + col] =
                *(const uint4*)(K + (size_t)(jb + row) * DIM + h * HD + col);
        }
        // ---- stage Vt tile [128 d][64 k]: straight copy from global Vt ----
#pragma unroll
        for (int u = 0; u < 4; ++u) {
            const int c = tid + 256 * u;              // 1024 chunks of 8
            const int d = c >> 3, k0c = (c & 7) * 8;
            *(uint4*)&VtL[d * 72 + k0c] = *(const uint4*)(vtg + (size_t)d * S + jb + k0c);
        }
        __syncthreads();

        // ---- QK^T: wave computes 16x64 scores ----
        facc4 sacc[4];
#pragma unroll
        for (int nt = 0; nt < 4; ++nt) {
#pragma unroll
            for (int r = 0; r < 4; ++r) sacc[nt][r] = 0.f;
#pragma unroll
            for (int kk = 0; kk < 4; ++kk) {
                const frag8 kfr = *(const frag8*)&Ks[(nt * 16 + mr) * 136 + kk * 32 + q * 8];
                sacc[nt] = __builtin_amdgcn_mfma_f32_16x16x32_bf16(qf[kk], kfr, sacc[nt], 0, 0, 0);
            }
        }

        float sv[4][4];
        float rmax[4] = {-1e30f, -1e30f, -1e30f, -1e30f};
#pragma unroll
        for (int nt = 0; nt < 4; ++nt) {
            const int j = jb + nt * 16 + mr;
#pragma unroll
            for (int r = 0; r < 4; ++r) {
                const int i = i0 + w * 16 + q * 4 + r;
                const bool valid = (j <= i) && (i - j < WIN);
                sv[nt][r] = valid ? sacc[nt][r] * scale : -1e30f;
                rmax[r] = fmaxf(rmax[r], sv[nt][r]);
            }
        }
#pragma unroll
        for (int msk = 1; msk <= 8; msk <<= 1)
#pragma unroll
            for (int r = 0; r < 4; ++r)
                rmax[r] = fmaxf(rmax[r], __shfl_xor(rmax[r], msk, 64));

        float alpha[4], rsum[4];
#pragma unroll
        for (int r = 0; r < 4; ++r) {
            const float mn = fmaxf(mrow[r], rmax[r]);
            alpha[r] = __expf(mrow[r] - mn);
            mrow[r] = mn;
            rsum[r] = 0.f;
        }
#pragma unroll
        for (int nt = 0; nt < 4; ++nt)
#pragma unroll
            for (int r = 0; r < 4; ++r) {
                const float pv = (sv[nt][r] > -1e29f) ? __expf(sv[nt][r] - mrow[r]) : 0.f;
                rsum[r] += pv;
                Ps[(w * 16 + q * 4 + r) * 72 + nt * 16 + mr] = (short)bfb(pv);
            }
#pragma unroll
        for (int msk = 1; msk <= 8; msk <<= 1)
#pragma unroll
            for (int r = 0; r < 4; ++r)
                rsum[r] += __shfl_xor(rsum[r], msk, 64);
#pragma unroll
        for (int r = 0; r < 4; ++r) lrow[r] = lrow[r] * alpha[r] + rsum[r];
#pragma unroll
        for (int dt = 0; dt < 8; ++dt)
#pragma unroll
            for (int r = 0; r < 4; ++r) oacc[dt][r] *= alpha[r];

        __syncthreads();

#pragma unroll
        for (int ks = 0; ks < 2; ++ks) {
            const frag8 pf = *(const frag8*)&Ps[(w * 16 + mr) * 72 + ks * 32 + q * 8];
#pragma unroll
            for (int dt = 0; dt < 8; ++dt) {
                const frag8 vf = *(const frag8*)&VtL[(dt * 16 + mr) * 72 + ks * 32 + q * 8];
                oacc[dt] = __builtin_amdgcn_mfma_f32_16x16x32_bf16(pf, vf, oacc[dt], 0, 0, 0);
            }
        }
    }

    float inv[4];
#pragma unroll
    for (int r = 0; r < 4; ++r) inv[r] = 1.0f / lrow[r];
#pragma unroll
    for (int dt = 0; dt < 8; ++dt)
#pragma unroll
        for (int r = 0; r < 4; ++r) {
            const int row = i0 + w * 16 + q * 4 + r;
            O[(size_t)row * DIM + h * HD + dt * 16 + mr] = fromF<bf16>(oacc[dt][r] * inv[r]);
        }
}

extern "C" void kernel_launch(void* const* d_in, const int* in_sizes, int n_in,
                              void* d_out, int out_size, void* d_ws, size_t ws_size,
                              hipStream_t stream) {
    const float* x  = (const float*)d_in[0];
    const float* Wq = (const float*)d_in[1];
    const float* Wk = (const float*)d_in[2];
    const float* Wv = (const float*)d_in[3];
    const float* Wo = (const float*)d_in[4];
    float* out = (float*)d_out;

    const int S = in_sizes[0] / DIM;          // 4096
    const size_t elems = (size_t)S * DIM;     // 8.39M
    const size_t wsz = (size_t)DIM * DIM;     // 4.19M

    bf16* Q    = (bf16*)d_ws;
    bf16* K    = Q + elems;
    bf16* V    = K + elems;
    bf16* Aat  = V + elems;
    bf16* xb   = Aat + elems;   // x(bf16) for QKV GEMM; dead after -> reused as Vt
    bf16* Wcat = xb + elems;    // [3*DIM][DIM]: Wq | Wk | Wv
    bf16* Wob  = Wcat + 3 * wsz;
    bf16* Vt   = xb;            // Vt[h][d][S], reuses xb (dead after QKV GEMM)
    // total ws use: (5*elems + 4*wsz)*2B = 117 MB

    cvt_f32_bf16<<<(int)(elems / 8 / 256), 256, 0, stream>>>(x, xb, (int)(elems / 8));
    cvt_f32_bf16<<<(int)(wsz / 8 / 256), 256, 0, stream>>>(Wq, Wcat, (int)(wsz / 8));
    cvt_f32_bf16<<<(int)(wsz / 8 / 256), 256, 0, stream>>>(Wk, Wcat + wsz, (int)(wsz / 8));
    cvt_f32_bf16<<<(int)(wsz / 8 / 256), 256, 0, stream>>>(Wv, Wcat + 2 * wsz, (int)(wsz / 8));
    cvt_f32_bf16<<<(int)(wsz / 8 / 256), 256, 0, stream>>>(Wo, Wob, (int)(wsz / 8));

    // fused QKV projection: [4096 x 2048] @ [6144 x 2048]^T, 256x256 8-phase kernel
    gemm256_8ph<bf16, true><<<dim3(3 * DIM / 256, S / 256), 512, 0, stream>>>(
        xb, Wcat, (bf16*)nullptr, Q, K, V, S, 3 * DIM, DIM);

    rope_qk_vec<<<(int)(elems / 8 / 256), 256, 0, stream>>>(Q, K, S);

    transp_v<<<dim3(S / 64, NH), 256, 0, stream>>>(V, Vt, S);

    flash_swa<<<dim3(S / 64, NH), 256, 0, stream>>>(Q, K, Vt, Aat, S);

    // Wo projection: only 128 wg at 256-tile -> keep 128-tile kernel (512 wg, 2/CU)
    gemm_bt_async<float><<<dim3(DIM / 128, S / 128), 256, 0, stream>>>(
        Aat, Wob, out, S, DIM, DIM);
}